// Round 9
// baseline (399.150 us; speedup 1.0000x reference)
//
#include <hip/hip_runtime.h>
#include <hip/hip_bf16.h>

typedef float f32x4 __attribute__((ext_vector_type(4)));
typedef __bf16 bf16x8 __attribute__((ext_vector_type(8)));

static __device__ __forceinline__ float lrelu(float x) { return x > 0.0f ? x : 0.01f * x; }

union bfu { __hip_bfloat162 b; unsigned u; };

// RTN split of a pair: hi-pair and residual lo-pair, each packed u32 (elem0 low, elem1 high).
// v == hi + lo exactly up to bf16(lo) rounding (~2^-18 relative).
static __device__ __forceinline__ void split_pair(float a, float b, unsigned& hu, unsigned& lu) {
    float2 f2; f2.x = a; f2.y = b;
    bfu h; h.b = __float22bfloat162_rn(f2);
    hu = h.u;
    float2 r2;
    r2.x = a - __uint_as_float(hu << 16);
    r2.y = b - __uint_as_float(hu & 0xFFFF0000u);
    bfu l; l.b = __float22bfloat162_rn(r2);
    lu = l.u;
}

// chunk-XOR swizzled element position in a [R][64] / [R][32] bf16 plane (16B chunks)
static __device__ __forceinline__ int swz64(int r, int k) {
    return r * 64 + ((((k >> 3) ^ (r & 7)) << 3) | (k & 7));
}
static __device__ __forceinline__ int swz32(int r, int k) {
    return r * 32 + ((((k >> 3) ^ (r & 3)) << 3) | (k & 7));
}

static __device__ __forceinline__ bf16x8 frag64(const unsigned short* pln, int r, int g2) {
    return *(const bf16x8*)(pln + r * 64 + ((g2 ^ (r & 7)) << 3));
}
static __device__ __forceinline__ bf16x8 frag32(const unsigned short* pln, int r, int g2) {
    return *(const bf16x8*)(pln + r * 32 + ((g2 ^ (r & 3)) << 3));
}

// pair at adjacent k (same 16B chunk, pos even) -> single b32 store per plane
static __device__ __forceinline__ void store_k2(unsigned short* ph, unsigned short* pl,
                                                int pos, float a, float b) {
    unsigned hu, lu; split_pair(a, b, hu, lu);
    *(unsigned*)(ph + pos) = hu;
    *(unsigned*)(pl + pos) = lu;
}
// pair at two arbitrary positions -> b16 stores (shared cvt_pk conversion)
static __device__ __forceinline__ void store_2(unsigned short* ph, unsigned short* pl,
                                               int pos0, int pos1, float a, float b) {
    unsigned hu, lu; split_pair(a, b, hu, lu);
    ph[pos0] = (unsigned short)hu; ph[pos1] = (unsigned short)(hu >> 16);
    pl[pos0] = (unsigned short)lu; pl[pos1] = (unsigned short)(lu >> 16);
}

// D = A*B + C with split-bf16 operands (hi*hi + lo*hi + hi*lo; lo*lo dropped).
static __device__ __forceinline__ f32x4 mfma3(bf16x8 ah, bf16x8 al, bf16x8 bh, bf16x8 bl, f32x4 c) {
    c = __builtin_amdgcn_mfma_f32_16x16x32_bf16(ah, bh, c, 0, 0, 0);
    c = __builtin_amdgcn_mfma_f32_16x16x32_bf16(al, bh, c, 0, 0, 0);
    c = __builtin_amdgcn_mfma_f32_16x16x32_bf16(ah, bl, c, 0, 0, 0);
    return c;
}

// ---- pipelined gather: issue (address calc + 4x float4 loads per level) ----
static __device__ __forceinline__ void issue_level(const float4* __restrict__ tbl, float u, float v,
                                                   int l, float4 r[4], float& wx, float& wy) {
    const int res = 16 << l;
    const float scale = (float)(res - 1);
    float px = u * scale + 0.5f;
    float py = v * scale + 0.5f;
    float fx = floorf(px), fy = floorf(py);
    wx = px - fx; wy = py - fy;
    int ix0 = min(max((int)fx, 0), res - 1);
    int iy0 = min(max((int)fy, 0), res - 1);
    int ix1 = min(ix0 + 1, res - 1);
    int iy1 = min(iy0 + 1, res - 1);
    unsigned base = (0x55555555u & ((1u << (2 * l)) - 1u)) * 256u;  // 256*(4^l-1)/3
    r[0] = tbl[base + iy0 * res + ix0];
    r[1] = tbl[base + iy0 * res + ix1];
    r[2] = tbl[base + iy1 * res + ix0];
    r[3] = tbl[base + iy1 * res + ix1];
}

static __device__ __forceinline__ void gather_issue(const float4* __restrict__ tbl, float u, float v,
                                                    float mips, float Lm1,
                                                    float4 r[8], float w[4], int cols[4]) {
    float clipped = fminf(mips, Lm1);
    float c0 = (Lm1 - clipped) * 4.0f;
    // Pin mul-then-add rounding (the int cast is a genuine discontinuity; must match JAX).
    asm volatile("" : "+v"(c0));
    cols[0] = (int)c0;
    cols[1] = (int)(c0 + 1.0f);
    cols[2] = (int)(c0 + 2.0f);
    cols[3] = (int)(c0 + 3.0f);
    int lA = cols[0] >> 2;
    int lB = cols[3] >> 2;
    issue_level(tbl, u, v, lA, &r[0], w[0], w[1]);
    issue_level(tbl, u, v, lB, &r[4], w[2], w[3]);
}

static __device__ __forceinline__ void gather_finish(const float4 r[8], const float w[4],
                                                     const int cols[4], float out[4]) {
    float A[4], Bv[4];
    {
        float owx = 1.0f - w[0], owy = 1.0f - w[1];
        A[0] = (r[0].x * owx + r[1].x * w[0]) * owy + (r[2].x * owx + r[3].x * w[0]) * w[1];
        A[1] = (r[0].y * owx + r[1].y * w[0]) * owy + (r[2].y * owx + r[3].y * w[0]) * w[1];
        A[2] = (r[0].z * owx + r[1].z * w[0]) * owy + (r[2].z * owx + r[3].z * w[0]) * w[1];
        A[3] = (r[0].w * owx + r[1].w * w[0]) * owy + (r[2].w * owx + r[3].w * w[0]) * w[1];
    }
    {
        float owx = 1.0f - w[2], owy = 1.0f - w[3];
        Bv[0] = (r[4].x * owx + r[5].x * w[2]) * owy + (r[6].x * owx + r[7].x * w[2]) * w[3];
        Bv[1] = (r[4].y * owx + r[5].y * w[2]) * owy + (r[6].y * owx + r[7].y * w[2]) * w[3];
        Bv[2] = (r[4].z * owx + r[5].z * w[2]) * owy + (r[6].z * owx + r[7].z * w[2]) * w[3];
        Bv[3] = (r[4].w * owx + r[5].w * w[2]) * owy + (r[6].w * owx + r[7].w * w[2]) * w[3];
    }
    int lA = cols[0] >> 2;
    #pragma unroll
    for (int j = 0; j < 4; ++j) {
        int lj = cols[j] >> 2;
        int fj = cols[j] & 3;
        float va = A[0];
        va = (fj == 1) ? A[1] : va;
        va = (fj == 2) ? A[2] : va;
        va = (fj == 3) ? A[3] : va;
        float vb = Bv[0];
        vb = (fj == 1) ? Bv[1] : vb;
        vb = (fj == 2) ? Bv[2] : vb;
        vb = (fj == 3) ? Bv[3] : vb;
        out[j] = (lj == lA) ? va : vb;
    }
}

static __device__ __forceinline__ void pe_compute(float coord, float pef[12]) {
    #pragma unroll
    for (int f = 0; f < 12; ++f) {
        float fr = (float)(1 << f);
        float xf = coord * fr;
        pef[f] = fabsf(xf - floorf(xf + 0.5f)) * 4.0f - 1.0f;
    }
}

// LDS: f32 lodw[64] + lodv[4][32], then bf16 planes:
//   win  hi/lo [64][32]   wh hi/lo [64][64]   wout hi/lo [16][64]
//   act  hi/lo [4][32][64]
#define LDS_BYTES ((64 + 128) * 4 + (2048 * 2 + 4096 * 2 + 1024 * 2 + 8192 * 2) * 2)

__global__ __launch_bounds__(256, 2) void tcnn_fwd(
    const float* __restrict__ x,
    const float4* __restrict__ g0,
    const float4* __restrict__ g1,
    const float* __restrict__ Win,   // (33,64)
    const float* __restrict__ Wh,    // (64,64)
    const float* __restrict__ Wout,  // (64,11)
    float* __restrict__ out,
    int npts)
{
    extern __shared__ float smemf[];
    float* s_lodw = smemf;                   // 64
    float* s_lodv = s_lodw + 64;             // 128
    unsigned short* s_win_h = (unsigned short*)(s_lodv + 128);
    unsigned short* s_win_l = s_win_h + 2048;
    unsigned short* s_wh_h  = s_win_l + 2048;
    unsigned short* s_wh_l  = s_wh_h + 4096;
    unsigned short* s_wo_h  = s_wh_l + 4096;
    unsigned short* s_wo_l  = s_wo_h + 1024;
    unsigned short* s_act_h = s_wo_l + 1024;   // 4 waves x 2048
    unsigned short* s_act_l = s_act_h + 8192;

    const int tid = threadIdx.x;

    // ---- one-time weight prep (pair-at-a-time along k) ----
    for (int q = tid; q < 1024; q += 256) {          // Win k<32
        int n = q >> 4, k0 = (q & 15) * 2;
        store_k2(s_win_h, s_win_l, swz32(n, k0), Win[k0 * 64 + n], Win[(k0 + 1) * 64 + n]);
    }
    for (int q = tid; q < 2048; q += 256) {          // Wh
        int n = q >> 5, k0 = (q & 31) * 2;
        store_k2(s_wh_h, s_wh_l, swz64(n, k0), Wh[k0 * 64 + n], Wh[(k0 + 1) * 64 + n]);
    }
    for (int q = tid; q < 512; q += 256) {           // Wout (n 11..15 zero)
        int n = q >> 5, k0 = (q & 31) * 2;
        float a = (n < 11) ? Wout[k0 * 11 + n] : 0.0f;
        float b = (n < 11) ? Wout[(k0 + 1) * 11 + n] : 0.0f;
        store_k2(s_wo_h, s_wo_l, swz64(n, k0), a, b);
    }
    if (tid < 64) s_lodw[tid] = Win[32 * 64 + tid];
    __syncthreads();

    const int wv = tid >> 6;
    const int l = tid & 63;
    const int g = l >> 4;       // 4-row group within 16x16 tile
    const int m = l & 15;       // col within tile
    const int half = l >> 5;
    const int p = l & 31;       // point within wave chunk

    unsigned short* act_h = s_act_h + wv * 2048;
    unsigned short* act_l = s_act_l + wv * 2048;
    float* lodv = s_lodv + wv * 32;

    // ---- weight B-fragments: direct bf16x8 loads, no unpacking ----
    bf16x8 w1h[4], w1l[4];
    #pragma unroll
    for (int Nt = 0; Nt < 4; ++Nt) {
        w1h[Nt] = frag32(s_win_h, Nt * 16 + m, g);
        w1l[Nt] = frag32(s_win_l, Nt * 16 + m, g);
    }
    bf16x8 w2h[4][2], w2l[4][2];
    #pragma unroll
    for (int Nt = 0; Nt < 4; ++Nt)
        #pragma unroll
        for (int ks = 0; ks < 2; ++ks) {
            w2h[Nt][ks] = frag64(s_wh_h, Nt * 16 + m, ks * 4 + g);
            w2l[Nt][ks] = frag64(s_wh_l, Nt * 16 + m, ks * 4 + g);
        }
    bf16x8 w3h[2], w3l[2];
    #pragma unroll
    for (int ks = 0; ks < 2; ++ks) {
        w3h[ks] = frag64(s_wo_h, m, ks * 4 + g);
        w3l[ks] = frag64(s_wo_l, m, ks * 4 + g);
    }

    const float4* __restrict__ mytbl = half ? g1 : g0;
    const float myLm1 = half ? 6.0f : 7.0f;
    const int STRIDE = gridDim.x * 128;

    int cb0 = (blockIdx.x * 4 + wv) * 32;
    if (cb0 + 31 >= npts) return;
    int nT = (npts - 32 - cb0) / STRIDE + 1;

    // ---- prologue: features of first chunk (latency exposed once) ----
    float pef[12], gff[4];
    float lodcur;
    {
        int gp = cb0 + p;
        float xu = x[gp * 3 + 0];
        float xv = x[gp * 3 + 1];
        float xl = x[gp * 3 + 2];
        float u = xu - floorf(xu);
        float vv = xv - floorf(xv);
        pe_compute(half ? vv : u, pef);
        float4 r[8]; float wgt[4]; int cols[4];
        gather_issue(mytbl, u, vv, xl * 7.0f, myLm1, r, wgt, cols);
        gather_finish(r, wgt, cols, gff);
        lodcur = xl;
    }

    for (int t = 0; t < nT; ++t) {
        int cb = cb0 + t * STRIDE;
        const bool pf = (t + 1 < nT);     // wave-uniform

        // ---- prefetch next x early (hidden under whole body) ----
        float xun = 0.0f, xvn = 0.0f, xln = 0.0f;
        if (pf) {
            int gpn = cb + STRIDE + p;
            xun = x[gpn * 3 + 0];
            xvn = x[gpn * 3 + 1];
            xln = x[gpn * 3 + 2];
        }

        // ---- store current features (paired cvt_pk, b32 plane writes) ----
        #pragma unroll
        for (int j = 0; j < 6; ++j)
            store_k2(act_h, act_l, swz64(p, half * 12 + 2 * j), pef[2 * j], pef[2 * j + 1]);
        store_k2(act_h, act_l, swz64(p, 24 + half * 4), gff[0], gff[1]);
        store_k2(act_h, act_l, swz64(p, 24 + half * 4 + 2), gff[2], gff[3]);
        if (half) lodv[p] = lodcur;
        __builtin_amdgcn_wave_barrier();

        // ---- layer 1: acc init = lod rank-1 (exact f32), then K=32 split-MFMA ----
        bf16x8 a1h[2], a1l[2];
        #pragma unroll
        for (int Mt = 0; Mt < 2; ++Mt) {
            a1h[Mt] = frag64(act_h, Mt * 16 + m, g);
            a1l[Mt] = frag64(act_l, Mt * 16 + m, g);
        }
        float lv[2][4];
        #pragma unroll
        for (int Mt = 0; Mt < 2; ++Mt)
            #pragma unroll
            for (int i = 0; i < 4; ++i)
                lv[Mt][i] = lodv[Mt * 16 + 4 * g + i];
        f32x4 acc1[2][4];
        #pragma unroll
        for (int Nt = 0; Nt < 4; ++Nt) {
            float wl = s_lodw[Nt * 16 + m];
            #pragma unroll
            for (int Mt = 0; Mt < 2; ++Mt)
                #pragma unroll
                for (int i = 0; i < 4; ++i)
                    acc1[Mt][Nt][i] = lv[Mt][i] * wl;
        }
        #pragma unroll
        for (int Nt = 0; Nt < 4; ++Nt)
            #pragma unroll
            for (int Mt = 0; Mt < 2; ++Mt)
                acc1[Mt][Nt] = mfma3(a1h[Mt], a1l[Mt], w1h[Nt], w1l[Nt], acc1[Mt][Nt]);

        // ---- next-iter feature start: PE + gather issue (hidden under layers 2/3) ----
        float4 r[8]; float wgt[4]; int cols[4];
        float un = 0.0f, vvn = 0.0f;
        if (pf) {
            un = xun - floorf(xun);
            vvn = xvn - floorf(xvn);
            gather_issue(mytbl, un, vvn, xln * 7.0f, myLm1, r, wgt, cols);
            pe_compute(half ? vvn : un, pef);
        }

        __builtin_amdgcn_wave_barrier();
        #pragma unroll
        for (int Mt = 0; Mt < 2; ++Mt)
            #pragma unroll
            for (int i = 0; i < 4; ++i) {
                int row = Mt * 16 + 4 * g + i;
                store_2(act_h, act_l, swz64(row, m), swz64(row, 16 + m),
                        lrelu(acc1[Mt][0][i]), lrelu(acc1[Mt][1][i]));
                store_2(act_h, act_l, swz64(row, 32 + m), swz64(row, 48 + m),
                        lrelu(acc1[Mt][2][i]), lrelu(acc1[Mt][3][i]));
            }
        __builtin_amdgcn_wave_barrier();

        // ---- layer 2: K=64 ----
        f32x4 acc2[2][4];
        #pragma unroll
        for (int Mt = 0; Mt < 2; ++Mt)
            #pragma unroll
            for (int Nt = 0; Nt < 4; ++Nt)
                acc2[Mt][Nt] = (f32x4){0.f, 0.f, 0.f, 0.f};
        #pragma unroll
        for (int Mt = 0; Mt < 2; ++Mt) {
            bf16x8 ah[2], al[2];
            #pragma unroll
            for (int ks = 0; ks < 2; ++ks) {
                ah[ks] = frag64(act_h, Mt * 16 + m, ks * 4 + g);
                al[ks] = frag64(act_l, Mt * 16 + m, ks * 4 + g);
            }
            #pragma unroll
            for (int Nt = 0; Nt < 4; ++Nt)
                #pragma unroll
                for (int ks = 0; ks < 2; ++ks)
                    acc2[Mt][Nt] = mfma3(ah[ks], al[ks], w2h[Nt][ks], w2l[Nt][ks], acc2[Mt][Nt]);
        }
        __builtin_amdgcn_wave_barrier();
        #pragma unroll
        for (int Mt = 0; Mt < 2; ++Mt)
            #pragma unroll
            for (int i = 0; i < 4; ++i) {
                int row = Mt * 16 + 4 * g + i;
                store_2(act_h, act_l, swz64(row, m), swz64(row, 16 + m),
                        lrelu(acc2[Mt][0][i]), lrelu(acc2[Mt][1][i]));
                store_2(act_h, act_l, swz64(row, 32 + m), swz64(row, 48 + m),
                        lrelu(acc2[Mt][2][i]), lrelu(acc2[Mt][3][i]));
            }
        __builtin_amdgcn_wave_barrier();

        // ---- layer 3: K=64, N=16 (11 valid) ----
        f32x4 acc3[2];
        acc3[0] = (f32x4){0.f, 0.f, 0.f, 0.f};
        acc3[1] = (f32x4){0.f, 0.f, 0.f, 0.f};
        #pragma unroll
        for (int Mt = 0; Mt < 2; ++Mt) {
            bf16x8 ah[2], al[2];
            #pragma unroll
            for (int ks = 0; ks < 2; ++ks) {
                ah[ks] = frag64(act_h, Mt * 16 + m, ks * 4 + g);
                al[ks] = frag64(act_l, Mt * 16 + m, ks * 4 + g);
            }
            #pragma unroll
            for (int ks = 0; ks < 2; ++ks)
                acc3[Mt] = mfma3(ah[ks], al[ks], w3h[ks], w3l[ks], acc3[Mt]);
        }
        #pragma unroll
        for (int Mt = 0; Mt < 2; ++Mt)
            #pragma unroll
            for (int i = 0; i < 4; ++i) {
                int row = Mt * 16 + 4 * g + i;
                float val = lrelu(acc3[Mt][i]);
                if (m < 11) out[(size_t)(cb + row) * 11 + m] = val;
            }
        __builtin_amdgcn_wave_barrier();

        // ---- finish next-iter features (loads have had layers 2/3 to land) ----
        if (pf) {
            gather_finish(r, wgt, cols, gff);
            lodcur = xln;
        }
    }
}

extern "C" void kernel_launch(void* const* d_in, const int* in_sizes, int n_in,
                              void* d_out, int out_size, void* d_ws, size_t ws_size,
                              hipStream_t stream) {
    const float* x = (const float*)d_in[0];
    const float4* g0 = (const float4*)d_in[1];
    const float4* g1 = (const float4*)d_in[2];
    const float* Win = (const float*)d_in[3];
    const float* Wh = (const float*)d_in[4];
    const float* Wout = (const float*)d_in[5];
    float* out = (float*)d_out;
    int npts = in_sizes[0] / 3;
    tcnn_fwd<<<512, 256, LDS_BYTES, stream>>>(x, g0, g1, Win, Wh, Wout, out, npts);
}

// Round 11
// 270.429 us; speedup vs baseline: 1.4760x; 1.4760x over previous
//
#include <hip/hip_runtime.h>
#include <hip/hip_bf16.h>

typedef float f32x4 __attribute__((ext_vector_type(4)));
typedef __bf16 bf16x8 __attribute__((ext_vector_type(8)));

static __device__ __forceinline__ float lrelu(float x) { return x > 0.0f ? x : 0.01f * x; }

union bfu { __hip_bfloat162 b; unsigned u; };

// RTN split of a pair: hi-pair and residual lo-pair, each packed u32 (elem0 low, elem1 high).
static __device__ __forceinline__ void split_pair(float a, float b, unsigned& hu, unsigned& lu) {
    float2 f2; f2.x = a; f2.y = b;
    bfu h; h.b = __float22bfloat162_rn(f2);
    hu = h.u;
    float2 r2;
    r2.x = a - __uint_as_float(hu << 16);
    r2.y = b - __uint_as_float(hu & 0xFFFF0000u);
    bfu l; l.b = __float22bfloat162_rn(r2);
    lu = l.u;
}

// chunk-XOR swizzled element position in a [R][64] / [R][32] bf16 plane (16B chunks)
static __device__ __forceinline__ int swz64(int r, int k) {
    return r * 64 + ((((k >> 3) ^ (r & 7)) << 3) | (k & 7));
}
static __device__ __forceinline__ int swz32(int r, int k) {
    return r * 32 + ((((k >> 3) ^ (r & 3)) << 3) | (k & 7));
}

static __device__ __forceinline__ bf16x8 frag64(const unsigned short* pln, int r, int g2) {
    return *(const bf16x8*)(pln + r * 64 + ((g2 ^ (r & 7)) << 3));
}
static __device__ __forceinline__ bf16x8 frag32(const unsigned short* pln, int r, int g2) {
    return *(const bf16x8*)(pln + r * 32 + ((g2 ^ (r & 3)) << 3));
}

// pair at adjacent k (same 16B chunk, pos even) -> single b32 store per plane
static __device__ __forceinline__ void store_k2(unsigned short* ph, unsigned short* pl,
                                                int pos, float a, float b) {
    unsigned hu, lu; split_pair(a, b, hu, lu);
    *(unsigned*)(ph + pos) = hu;
    *(unsigned*)(pl + pos) = lu;
}
// pair at two arbitrary positions -> b16 stores (shared cvt_pk conversion)
static __device__ __forceinline__ void store_2(unsigned short* ph, unsigned short* pl,
                                               int pos0, int pos1, float a, float b) {
    unsigned hu, lu; split_pair(a, b, hu, lu);
    ph[pos0] = (unsigned short)hu; ph[pos1] = (unsigned short)(hu >> 16);
    pl[pos0] = (unsigned short)lu; pl[pos1] = (unsigned short)(lu >> 16);
}

// D = A*B + C with split-bf16 operands (hi*hi + lo*hi + hi*lo; lo*lo dropped).
static __device__ __forceinline__ f32x4 mfma3(bf16x8 ah, bf16x8 al, bf16x8 bh, bf16x8 bl, f32x4 c) {
    c = __builtin_amdgcn_mfma_f32_16x16x32_bf16(ah, bh, c, 0, 0, 0);
    c = __builtin_amdgcn_mfma_f32_16x16x32_bf16(al, bh, c, 0, 0, 0);
    c = __builtin_amdgcn_mfma_f32_16x16x32_bf16(ah, bl, c, 0, 0, 0);
    return c;
}

// ---- gather: issue (address calc + 4x float4 loads per level) ----
static __device__ __forceinline__ void issue_level(const float4* __restrict__ tbl, float u, float v,
                                                   int l, float4 r[4], float& wx, float& wy) {
    const int res = 16 << l;
    const float scale = (float)(res - 1);
    float px = u * scale + 0.5f;
    float py = v * scale + 0.5f;
    float fx = floorf(px), fy = floorf(py);
    wx = px - fx; wy = py - fy;
    int ix0 = min(max((int)fx, 0), res - 1);
    int iy0 = min(max((int)fy, 0), res - 1);
    int ix1 = min(ix0 + 1, res - 1);
    int iy1 = min(iy0 + 1, res - 1);
    unsigned base = (0x55555555u & ((1u << (2 * l)) - 1u)) * 256u;  // 256*(4^l-1)/3
    r[0] = tbl[base + iy0 * res + ix0];
    r[1] = tbl[base + iy0 * res + ix1];
    r[2] = tbl[base + iy1 * res + ix0];
    r[3] = tbl[base + iy1 * res + ix1];
}

static __device__ __forceinline__ void gather_issue(const float4* __restrict__ tbl, float u, float v,
                                                    float mips, float Lm1,
                                                    float4 r[8], float w[4], int cols[4]) {
    float clipped = fminf(mips, Lm1);
    float c0 = (Lm1 - clipped) * 4.0f;
    // Pin mul-then-add rounding (the int cast is a genuine discontinuity; must match JAX).
    asm volatile("" : "+v"(c0));
    cols[0] = (int)c0;
    cols[1] = (int)(c0 + 1.0f);
    cols[2] = (int)(c0 + 2.0f);
    cols[3] = (int)(c0 + 3.0f);
    int lA = cols[0] >> 2;
    int lB = cols[3] >> 2;
    issue_level(tbl, u, v, lA, &r[0], w[0], w[1]);
    issue_level(tbl, u, v, lB, &r[4], w[2], w[3]);
}

static __device__ __forceinline__ void gather_finish(const float4 r[8], const float w[4],
                                                     const int cols[4], float out[4]) {
    float A[4], Bv[4];
    {
        float owx = 1.0f - w[0], owy = 1.0f - w[1];
        A[0] = (r[0].x * owx + r[1].x * w[0]) * owy + (r[2].x * owx + r[3].x * w[0]) * w[1];
        A[1] = (r[0].y * owx + r[1].y * w[0]) * owy + (r[2].y * owx + r[3].y * w[0]) * w[1];
        A[2] = (r[0].z * owx + r[1].z * w[0]) * owy + (r[2].z * owx + r[3].z * w[0]) * w[1];
        A[3] = (r[0].w * owx + r[1].w * w[0]) * owy + (r[2].w * owx + r[3].w * w[0]) * w[1];
    }
    {
        float owx = 1.0f - w[2], owy = 1.0f - w[3];
        Bv[0] = (r[4].x * owx + r[5].x * w[2]) * owy + (r[6].x * owx + r[7].x * w[2]) * w[3];
        Bv[1] = (r[4].y * owx + r[5].y * w[2]) * owy + (r[6].y * owx + r[7].y * w[2]) * w[3];
        Bv[2] = (r[4].z * owx + r[5].z * w[2]) * owy + (r[6].z * owx + r[7].z * w[2]) * w[3];
        Bv[3] = (r[4].w * owx + r[5].w * w[2]) * owy + (r[6].w * owx + r[7].w * w[2]) * w[3];
    }
    int lA = cols[0] >> 2;
    #pragma unroll
    for (int j = 0; j < 4; ++j) {
        int lj = cols[j] >> 2;
        int fj = cols[j] & 3;
        float va = A[0];
        va = (fj == 1) ? A[1] : va;
        va = (fj == 2) ? A[2] : va;
        va = (fj == 3) ? A[3] : va;
        float vb = Bv[0];
        vb = (fj == 1) ? Bv[1] : vb;
        vb = (fj == 2) ? Bv[2] : vb;
        vb = (fj == 3) ? Bv[3] : vb;
        out[j] = (lj == lA) ? va : vb;
    }
}

static __device__ __forceinline__ void pe_compute(float coord, float pef[12]) {
    #pragma unroll
    for (int f = 0; f < 12; ++f) {
        float fr = (float)(1 << f);
        float xf = coord * fr;
        pef[f] = fabsf(xf - floorf(xf + 0.5f)) * 4.0f - 1.0f;
    }
}

// LDS: f32 lodw[64] + lodv[4][32], then bf16 planes:
//   win  hi/lo [64][32]   wh hi/lo [64][64]   wout hi/lo [16][64]
//   act  hi/lo [4][32][64]
#define LDS_BYTES ((64 + 128) * 4 + (2048 * 2 + 4096 * 2 + 1024 * 2 + 8192 * 2) * 2)

__global__ __launch_bounds__(256, 2) void tcnn_fwd(
    const float* __restrict__ x,
    const float4* __restrict__ g0,
    const float4* __restrict__ g1,
    const float* __restrict__ Win,   // (33,64)
    const float* __restrict__ Wh,    // (64,64)
    const float* __restrict__ Wout,  // (64,11)
    float* __restrict__ out,
    int npts)
{
    extern __shared__ float smemf[];
    float* s_lodw = smemf;                   // 64
    float* s_lodv = s_lodw + 64;             // 128
    unsigned short* s_win_h = (unsigned short*)(s_lodv + 128);
    unsigned short* s_win_l = s_win_h + 2048;
    unsigned short* s_wh_h  = s_win_l + 2048;
    unsigned short* s_wh_l  = s_wh_h + 4096;
    unsigned short* s_wo_h  = s_wh_l + 4096;
    unsigned short* s_wo_l  = s_wo_h + 1024;
    unsigned short* s_act_h = s_wo_l + 1024;   // 4 waves x 2048
    unsigned short* s_act_l = s_act_h + 8192;

    const int tid = threadIdx.x;

    // ---- one-time weight prep (pair-at-a-time along k) ----
    for (int q = tid; q < 1024; q += 256) {          // Win k<32
        int n = q >> 4, k0 = (q & 15) * 2;
        store_k2(s_win_h, s_win_l, swz32(n, k0), Win[k0 * 64 + n], Win[(k0 + 1) * 64 + n]);
    }
    for (int q = tid; q < 2048; q += 256) {          // Wh
        int n = q >> 5, k0 = (q & 31) * 2;
        store_k2(s_wh_h, s_wh_l, swz64(n, k0), Wh[k0 * 64 + n], Wh[(k0 + 1) * 64 + n]);
    }
    for (int q = tid; q < 512; q += 256) {           // Wout (n 11..15 zero)
        int n = q >> 5, k0 = (q & 31) * 2;
        float a = (n < 11) ? Wout[k0 * 11 + n] : 0.0f;
        float b = (n < 11) ? Wout[(k0 + 1) * 11 + n] : 0.0f;
        store_k2(s_wo_h, s_wo_l, swz64(n, k0), a, b);
    }
    if (tid < 64) s_lodw[tid] = Win[32 * 64 + tid];
    __syncthreads();

    const int wv = tid >> 6;
    const int l = tid & 63;
    const int g = l >> 4;       // 4-row group within 16x16 tile
    const int m = l & 15;       // col within tile
    const int half = l >> 5;
    const int p = l & 31;       // point within wave chunk

    unsigned short* act_h = s_act_h + wv * 2048;
    unsigned short* act_l = s_act_l + wv * 2048;
    float* lodv = s_lodv + wv * 32;

    const float4* __restrict__ mytbl = half ? g1 : g0;
    const float myLm1 = half ? 6.0f : 7.0f;
    const int STRIDE = gridDim.x * 128;

    int cb0 = (blockIdx.x * 4 + wv) * 32;
    if (cb0 + 31 >= npts) return;

    for (int cb = cb0; cb + 31 < npts; cb += STRIDE) {
        // ---- feature build: lane p does u-half, lane p+32 does v-half of point cb+p ----
        int gp = cb + p;
        float xu = x[gp * 3 + 0];
        float xv = x[gp * 3 + 1];
        float xl = x[gp * 3 + 2];
        float u = xu - floorf(xu);
        float vv = xv - floorf(xv);

        float4 r[8]; float wgt[4]; int cols[4];
        gather_issue(mytbl, u, vv, xl * 7.0f, myLm1, r, wgt, cols);
        float pef[12];
        pe_compute(half ? vv : u, pef);       // VALU work overlaps the gather vmcnt wait
        float gff[4];
        gather_finish(r, wgt, cols, gff);

        // ---- store features (paired cvt_pk, b32 plane writes) ----
        #pragma unroll
        for (int j = 0; j < 6; ++j)
            store_k2(act_h, act_l, swz64(p, half * 12 + 2 * j), pef[2 * j], pef[2 * j + 1]);
        store_k2(act_h, act_l, swz64(p, 24 + half * 4), gff[0], gff[1]);
        store_k2(act_h, act_l, swz64(p, 24 + half * 4 + 2), gff[2], gff[3]);
        if (half) lodv[p] = xl;
        __builtin_amdgcn_wave_barrier();

        // ---- layer 1: acc init = lod rank-1 (exact f32), then K=32 split-MFMA ----
        bf16x8 a1h[2], a1l[2];
        #pragma unroll
        for (int Mt = 0; Mt < 2; ++Mt) {
            a1h[Mt] = frag64(act_h, Mt * 16 + m, g);
            a1l[Mt] = frag64(act_l, Mt * 16 + m, g);
        }
        float lv[2][4];
        #pragma unroll
        for (int Mt = 0; Mt < 2; ++Mt)
            #pragma unroll
            for (int i = 0; i < 4; ++i)
                lv[Mt][i] = lodv[Mt * 16 + 4 * g + i];
        f32x4 acc1[2][4];
        #pragma unroll
        for (int Nt = 0; Nt < 4; ++Nt) {
            float wl = s_lodw[Nt * 16 + m];
            #pragma unroll
            for (int Mt = 0; Mt < 2; ++Mt)
                #pragma unroll
                for (int i = 0; i < 4; ++i)
                    acc1[Mt][Nt][i] = lv[Mt][i] * wl;
        }
        #pragma unroll
        for (int Nt = 0; Nt < 4; ++Nt) {
            bf16x8 bh = frag32(s_win_h, Nt * 16 + m, g);   // weight frag read AT USE
            bf16x8 bl = frag32(s_win_l, Nt * 16 + m, g);
            #pragma unroll
            for (int Mt = 0; Mt < 2; ++Mt)
                acc1[Mt][Nt] = mfma3(a1h[Mt], a1l[Mt], bh, bl, acc1[Mt][Nt]);
        }
        __builtin_amdgcn_wave_barrier();
        #pragma unroll
        for (int Mt = 0; Mt < 2; ++Mt)
            #pragma unroll
            for (int i = 0; i < 4; ++i) {
                int row = Mt * 16 + 4 * g + i;
                store_2(act_h, act_l, swz64(row, m), swz64(row, 16 + m),
                        lrelu(acc1[Mt][0][i]), lrelu(acc1[Mt][1][i]));
                store_2(act_h, act_l, swz64(row, 32 + m), swz64(row, 48 + m),
                        lrelu(acc1[Mt][2][i]), lrelu(acc1[Mt][3][i]));
            }
        __builtin_amdgcn_wave_barrier();

        // ---- layer 2: K=64 ----
        bf16x8 a2h[2][2], a2l[2][2];
        #pragma unroll
        for (int Mt = 0; Mt < 2; ++Mt)
            #pragma unroll
            for (int ks = 0; ks < 2; ++ks) {
                a2h[Mt][ks] = frag64(act_h, Mt * 16 + m, ks * 4 + g);
                a2l[Mt][ks] = frag64(act_l, Mt * 16 + m, ks * 4 + g);
            }
        f32x4 acc2[2][4];
        #pragma unroll
        for (int Mt = 0; Mt < 2; ++Mt)
            #pragma unroll
            for (int Nt = 0; Nt < 4; ++Nt)
                acc2[Mt][Nt] = (f32x4){0.f, 0.f, 0.f, 0.f};
        #pragma unroll
        for (int Nt = 0; Nt < 4; ++Nt)
            #pragma unroll
            for (int ks = 0; ks < 2; ++ks) {
                bf16x8 bh = frag64(s_wh_h, Nt * 16 + m, ks * 4 + g);
                bf16x8 bl = frag64(s_wh_l, Nt * 16 + m, ks * 4 + g);
                #pragma unroll
                for (int Mt = 0; Mt < 2; ++Mt)
                    acc2[Mt][Nt] = mfma3(a2h[Mt][ks], a2l[Mt][ks], bh, bl, acc2[Mt][Nt]);
            }
        __builtin_amdgcn_wave_barrier();
        #pragma unroll
        for (int Mt = 0; Mt < 2; ++Mt)
            #pragma unroll
            for (int i = 0; i < 4; ++i) {
                int row = Mt * 16 + 4 * g + i;
                store_2(act_h, act_l, swz64(row, m), swz64(row, 16 + m),
                        lrelu(acc2[Mt][0][i]), lrelu(acc2[Mt][1][i]));
                store_2(act_h, act_l, swz64(row, 32 + m), swz64(row, 48 + m),
                        lrelu(acc2[Mt][2][i]), lrelu(acc2[Mt][3][i]));
            }
        __builtin_amdgcn_wave_barrier();

        // ---- layer 3: K=64, N=16 (11 valid) ----
        bf16x8 a3h[2][2], a3l[2][2];
        #pragma unroll
        for (int Mt = 0; Mt < 2; ++Mt)
            #pragma unroll
            for (int ks = 0; ks < 2; ++ks) {
                a3h[Mt][ks] = frag64(act_h, Mt * 16 + m, ks * 4 + g);
                a3l[Mt][ks] = frag64(act_l, Mt * 16 + m, ks * 4 + g);
            }
        f32x4 acc3[2];
        acc3[0] = (f32x4){0.f, 0.f, 0.f, 0.f};
        acc3[1] = (f32x4){0.f, 0.f, 0.f, 0.f};
        #pragma unroll
        for (int ks = 0; ks < 2; ++ks) {
            bf16x8 bh = frag64(s_wo_h, m, ks * 4 + g);
            bf16x8 bl = frag64(s_wo_l, m, ks * 4 + g);
            #pragma unroll
            for (int Mt = 0; Mt < 2; ++Mt)
                acc3[Mt] = mfma3(a3h[Mt][ks], a3l[Mt][ks], bh, bl, acc3[Mt]);
        }
        #pragma unroll
        for (int Mt = 0; Mt < 2; ++Mt)
            #pragma unroll
            for (int i = 0; i < 4; ++i) {
                int row = Mt * 16 + 4 * g + i;
                float val = lrelu(acc3[Mt][i]);
                if (m < 11) out[(size_t)(cb + row) * 11 + m] = val;
            }
        __builtin_amdgcn_wave_barrier();
    }
}

extern "C" void kernel_launch(void* const* d_in, const int* in_sizes, int n_in,
                              void* d_out, int out_size, void* d_ws, size_t ws_size,
                              hipStream_t stream) {
    const float* x = (const float*)d_in[0];
    const float4* g0 = (const float4*)d_in[1];
    const float4* g1 = (const float4*)d_in[2];
    const float* Win = (const float*)d_in[3];
    const float* Wh = (const float*)d_in[4];
    const float* Wout = (const float*)d_in[5];
    float* out = (float*)d_out;
    int npts = in_sizes[0] / 3;
    tcnn_fwd<<<512, 256, LDS_BYTES, stream>>>(x, g0, g1, Win, Wh, Wout, out, npts);
}